// Round 1
// baseline (428.424 us; speedup 1.0000x reference)
//
#include <hip/hip_runtime.h>
#include <math.h>

// ---------------------------------------------------------------------------
// GCN fraud-model forward:
//   out = A(relu(A(x*sig(mask) @ W1) + b1) @ (W2@Wc)) + (b2@Wc + bc)
// using linearity of aggregation A to fold W2@Wc -> [128,2].
// ---------------------------------------------------------------------------

// ---------- tiny prep: sigmoid(mask), Wf = W2@Wc [128,2], bf = b2@Wc + bc ----
__global__ void prep_kernel(const float* __restrict__ fmask, const float* __restrict__ W2,
                            const float* __restrict__ b2, const float* __restrict__ Wc,
                            const float* __restrict__ bc, float* __restrict__ sm,
                            float* __restrict__ Wf, float* __restrict__ bf) {
  int t = threadIdx.x;
  if (t < 128) {
    sm[t] = 1.0f / (1.0f + expf(-fmask[t]));
    float w0 = 0.f, w1 = 0.f;
    for (int k = 0; k < 128; ++k) {
      float v = W2[t * 128 + k];
      w0 = fmaf(v, Wc[k * 2 + 0], w0);
      w1 = fmaf(v, Wc[k * 2 + 1], w1);
    }
    Wf[t * 2 + 0] = w0;
    Wf[t * 2 + 1] = w1;
  }
  if (t < 2) {
    float s = bc[t];
    for (int k = 0; k < 128; ++k) s = fmaf(b2[k], Wc[k * 2 + t], s);
    bf[t] = s;
  }
}

// ---------- degree count over dst ----------
__global__ void count_kernel(const int* __restrict__ dst, int* __restrict__ counts, int E) {
  int e = blockIdx.x * blockDim.x + threadIdx.x;
  if (e < E) atomicAdd(&counts[dst[e]], 1);
}

// ---------- dinv = rsqrt(indeg + 1)  (self-loop) ----------
__global__ void dinv_kernel(const int* __restrict__ counts, float* __restrict__ dinv, int n) {
  int i = blockIdx.x * blockDim.x + threadIdx.x;
  if (i < n) dinv[i] = rsqrtf((float)(counts[i] + 1));
}

// ---------- 3-phase exclusive scan of counts (chunks of 1024) ----------
__global__ void scanA_kernel(const int* __restrict__ counts, int* __restrict__ bsum, int n) {
  __shared__ int sh[256];
  int t = threadIdx.x;
  int base = blockIdx.x * 1024 + t * 4;
  int s = 0;
#pragma unroll
  for (int j = 0; j < 4; ++j) {
    int idx = base + j;
    if (idx < n) s += counts[idx];
  }
  sh[t] = s;
  __syncthreads();
#pragma unroll
  for (int m = 128; m > 0; m >>= 1) {
    if (t < m) sh[t] += sh[t + m];
    __syncthreads();
  }
  if (t == 0) bsum[blockIdx.x] = sh[0];
}

__global__ void scanB_kernel(int* __restrict__ bsum, int nb) {
  __shared__ int sh[256];
  int t = threadIdx.x;
  int v = (t < nb) ? bsum[t] : 0;
  sh[t] = v;
  __syncthreads();
  for (int off = 1; off < 256; off <<= 1) {
    int add = (t >= off) ? sh[t - off] : 0;
    __syncthreads();
    sh[t] += add;
    __syncthreads();
  }
  if (t < nb) bsum[t] = sh[t] - v;  // exclusive
}

__global__ void scanC_kernel(const int* __restrict__ counts, const int* __restrict__ bsum,
                             int* __restrict__ offsets, int* __restrict__ cursor, int n) {
  __shared__ int sh[256];
  int t = threadIdx.x;
  int base = blockIdx.x * 1024 + t * 4;
  int c[4];
  int loc = 0;
#pragma unroll
  for (int j = 0; j < 4; ++j) {
    int idx = base + j;
    c[j] = (idx < n) ? counts[idx] : 0;
    loc += c[j];
  }
  sh[t] = loc;
  __syncthreads();
  for (int off = 1; off < 256; off <<= 1) {
    int add = (t >= off) ? sh[t - off] : 0;
    __syncthreads();
    sh[t] += add;
    __syncthreads();
  }
  int run = bsum[blockIdx.x] + sh[t] - loc;
#pragma unroll
  for (int j = 0; j < 4; ++j) {
    int idx = base + j;
    if (idx < n) {
      offsets[idx] = run;
      cursor[idx] = run;
    }
    run += c[j];
  }
}

// ---------- CSR fill (bucket edges by dst) ----------
__global__ void fill_kernel(const int* __restrict__ src, const int* __restrict__ dst,
                            int* __restrict__ cursor, int* __restrict__ csr, int E) {
  int e = blockIdx.x * blockDim.x + threadIdx.x;
  if (e < E) {
    int d = dst[e];
    int p = atomicAdd(&cursor[d], 1);
    csr[p] = src[e];
  }
}

// ---------- GEMM1: H1 = (x * sm) @ W1, W1 in LDS, 32-row tiles, 4x4/thread ---
__global__ __launch_bounds__(256, 1) void gemm1_kernel(const float* __restrict__ x,
                                                       const float* __restrict__ W1,
                                                       const float* __restrict__ sm,
                                                       float* __restrict__ H1, int n) {
  __shared__ float lw[128 * 128];   // 64 KB
  __shared__ float lxt[128 * 36];   // transposed x tile, padded stride 36
  __shared__ float lsm[128];
  int t = threadIdx.x;
  if (t < 128) lsm[t] = sm[t];
  for (int i = t; i < 16384; i += 256) lw[i] = W1[i];
  __syncthreads();

  int rpb = (((n + gridDim.x - 1) / gridDim.x) + 31) & ~31;
  int r0 = blockIdx.x * rpb;
  int rend = min(n, r0 + rpb);
  int tc = t & 31, rg = t >> 5;

  for (int rb = r0; rb < rend; rb += 32) {
    __syncthreads();
    {
      int lr = t >> 3;              // 0..31 local row
      int row = rb + lr;
      int cbase = (t & 7) * 16;     // 16 consecutive features
      if (row < n) {
        const float* xp = x + (size_t)row * 128 + cbase;
#pragma unroll
        for (int j = 0; j < 4; ++j) {
          float4 v = *(const float4*)(xp + 4 * j);
          int c = cbase + 4 * j;
          lxt[(c + 0) * 36 + lr] = v.x * lsm[c + 0];
          lxt[(c + 1) * 36 + lr] = v.y * lsm[c + 1];
          lxt[(c + 2) * 36 + lr] = v.z * lsm[c + 2];
          lxt[(c + 3) * 36 + lr] = v.w * lsm[c + 3];
        }
      } else {
#pragma unroll
        for (int j = 0; j < 16; ++j) lxt[(cbase + j) * 36 + lr] = 0.f;
      }
    }
    __syncthreads();

    float4 a0 = {0, 0, 0, 0}, a1 = {0, 0, 0, 0}, a2 = {0, 0, 0, 0}, a3 = {0, 0, 0, 0};
    const float* wp = lw + tc * 4;
    const float* xp = lxt + rg * 4;
#pragma unroll 8
    for (int k = 0; k < 128; ++k) {
      float4 wv = *(const float4*)(wp + k * 128);
      float4 xv = *(const float4*)(xp + k * 36);
      a0.x = fmaf(xv.x, wv.x, a0.x); a0.y = fmaf(xv.x, wv.y, a0.y);
      a0.z = fmaf(xv.x, wv.z, a0.z); a0.w = fmaf(xv.x, wv.w, a0.w);
      a1.x = fmaf(xv.y, wv.x, a1.x); a1.y = fmaf(xv.y, wv.y, a1.y);
      a1.z = fmaf(xv.y, wv.z, a1.z); a1.w = fmaf(xv.y, wv.w, a1.w);
      a2.x = fmaf(xv.z, wv.x, a2.x); a2.y = fmaf(xv.z, wv.y, a2.y);
      a2.z = fmaf(xv.z, wv.z, a2.z); a2.w = fmaf(xv.z, wv.w, a2.w);
      a3.x = fmaf(xv.w, wv.x, a3.x); a3.y = fmaf(xv.w, wv.y, a3.y);
      a3.z = fmaf(xv.w, wv.z, a3.z); a3.w = fmaf(xv.w, wv.w, a3.w);
    }
    int colb = tc * 4;
    int rowb = rb + rg * 4;
    if (rowb + 0 < n) *(float4*)(H1 + (size_t)(rowb + 0) * 128 + colb) = a0;
    if (rowb + 1 < n) *(float4*)(H1 + (size_t)(rowb + 1) * 128 + colb) = a1;
    if (rowb + 2 < n) *(float4*)(H1 + (size_t)(rowb + 2) * 128 + colb) = a2;
    if (rowb + 3 < n) *(float4*)(H1 + (size_t)(rowb + 3) * 128 + colb) = a3;
  }
}

// ---------- agg1 (wave per node): h1 = relu(A(H1pre)+b1) in regs, Z = h1@Wf --
__global__ __launch_bounds__(256) void agg1_kernel(
    const float* __restrict__ H1, const int* __restrict__ csr,
    const int* __restrict__ offsets, const int* __restrict__ counts,
    const float* __restrict__ dinv, const float* __restrict__ b1,
    const float* __restrict__ Wf, float* __restrict__ Z, int n) {
  int lane = threadIdx.x & 63;
  int node = blockIdx.x * 4 + (threadIdx.x >> 6);
  if (node >= n) return;
  int c0 = lane * 2;

  float di = dinv[node];
  float2 acc = *(const float2*)(H1 + (size_t)node * 128 + c0);  // self-loop
  float dii = di * di;
  acc.x *= dii;
  acc.y *= dii;

  int off = offsets[node];
  int cnt = counts[node];
  int e = 0;
  for (; e + 2 <= cnt; e += 2) {
    int s0 = csr[off + e];
    int s1 = csr[off + e + 1];
    float w0 = dinv[s0] * di;
    float w1 = dinv[s1] * di;
    float2 h0 = *(const float2*)(H1 + (size_t)s0 * 128 + c0);
    float2 h1 = *(const float2*)(H1 + (size_t)s1 * 128 + c0);
    acc.x = fmaf(h0.x, w0, acc.x); acc.y = fmaf(h0.y, w0, acc.y);
    acc.x = fmaf(h1.x, w1, acc.x); acc.y = fmaf(h1.y, w1, acc.y);
  }
  if (e < cnt) {
    int s0 = csr[off + e];
    float w0 = dinv[s0] * di;
    float2 h0 = *(const float2*)(H1 + (size_t)s0 * 128 + c0);
    acc.x = fmaf(h0.x, w0, acc.x); acc.y = fmaf(h0.y, w0, acc.y);
  }

  float2 bb = *(const float2*)(b1 + c0);
  float v0 = acc.x + bb.x; v0 = v0 > 0.f ? v0 : 0.f;
  float v1 = acc.y + bb.y; v1 = v1 > 0.f ? v1 : 0.f;

  float4 wv = *(const float4*)(Wf + c0 * 2);  // {Wf[c0][0],Wf[c0][1],Wf[c0+1][0],Wf[c0+1][1]}
  float z0 = v0 * wv.x + v1 * wv.z;
  float z1 = v0 * wv.y + v1 * wv.w;
#pragma unroll
  for (int m = 32; m > 0; m >>= 1) {
    z0 += __shfl_xor(z0, m, 64);
    z1 += __shfl_xor(z1, m, 64);
  }
  if (lane == 0) {
    Z[(size_t)node * 2 + 0] = z0;
    Z[(size_t)node * 2 + 1] = z1;
  }
}

// ---------- agg2 (thread per node): out = A(Z) + bf ----------
__global__ void agg2_kernel(const float* __restrict__ Zbuf, const int* __restrict__ csr,
                            const int* __restrict__ offsets, const int* __restrict__ counts,
                            const float* __restrict__ dinv, const float* __restrict__ bf,
                            float* __restrict__ out, int n) {
  int i = blockIdx.x * blockDim.x + threadIdx.x;
  if (i >= n) return;
  float di = dinv[i];
  float2 z = *(const float2*)(Zbuf + (size_t)i * 2);
  float dii = di * di;
  float ax = z.x * dii, ay = z.y * dii;
  int off = offsets[i], cnt = counts[i];
  for (int e = 0; e < cnt; ++e) {
    int s = csr[off + e];
    float w = dinv[s] * di;
    float2 zs = *(const float2*)(Zbuf + (size_t)s * 2);
    ax = fmaf(zs.x, w, ax);
    ay = fmaf(zs.y, w, ay);
  }
  out[(size_t)i * 2 + 0] = ax + bf[0];
  out[(size_t)i * 2 + 1] = ay + bf[1];
}

extern "C" void kernel_launch(void* const* d_in, const int* in_sizes, int n_in,
                              void* d_out, int out_size, void* d_ws, size_t ws_size,
                              hipStream_t stream) {
  const float* x = (const float*)d_in[0];
  const int* ei = (const int*)d_in[1];
  const float* fmask = (const float*)d_in[2];
  const float* W1 = (const float*)d_in[3];
  const float* b1 = (const float*)d_in[4];
  const float* W2 = (const float*)d_in[5];
  const float* b2 = (const float*)d_in[6];
  const float* Wc = (const float*)d_in[7];
  const float* bc = (const float*)d_in[8];

  int N = in_sizes[0] / 128;
  int E = in_sizes[1] / 2;
  const int* src = ei;
  const int* dst = ei + E;

  char* base = (char*)d_ws;
  size_t o = 0;
  auto take = [&](size_t bytes) -> char* {
    char* p = base + o;
    o = (o + bytes + 255) & ~(size_t)255;
    return p;
  };
  int* counts = (int*)take((size_t)N * 4);
  int* offsets = (int*)take((size_t)N * 4);
  int* cursor = (int*)take((size_t)N * 4);
  int* bsum = (int*)take(256 * 4);
  float* dinv = (float*)take((size_t)N * 4);
  int* csr = (int*)take((size_t)E * 4);
  float* H1 = (float*)take((size_t)N * 128 * 4);
  float* Zb = (float*)take((size_t)N * 2 * 4);
  float* sm = (float*)take(128 * 4);
  float* Wf = (float*)take(256 * 4);
  float* bf = (float*)take(2 * 4);
  (void)ws_size;
  (void)n_in;
  (void)out_size;

  hipMemsetAsync(counts, 0, (size_t)N * 4, stream);
  prep_kernel<<<1, 128, 0, stream>>>(fmask, W2, b2, Wc, bc, sm, Wf, bf);
  count_kernel<<<(E + 255) / 256, 256, 0, stream>>>(dst, counts, E);
  dinv_kernel<<<(N + 255) / 256, 256, 0, stream>>>(counts, dinv, N);
  int nb = (N + 1023) / 1024;
  scanA_kernel<<<nb, 256, 0, stream>>>(counts, bsum, N);
  scanB_kernel<<<1, 256, 0, stream>>>(bsum, nb);
  scanC_kernel<<<nb, 256, 0, stream>>>(counts, bsum, offsets, cursor, N);
  fill_kernel<<<(E + 255) / 256, 256, 0, stream>>>(src, dst, cursor, csr, E);
  gemm1_kernel<<<256, 256, 0, stream>>>(x, W1, sm, H1, N);
  agg1_kernel<<<(N + 3) / 4, 256, 0, stream>>>(H1, csr, offsets, counts, dinv, b1, Wf, Zb, N);
  agg2_kernel<<<(N + 255) / 256, 256, 0, stream>>>(Zb, csr, offsets, counts, dinv, bf,
                                                   (float*)d_out, N);
}

// Round 2
// 381.475 us; speedup vs baseline: 1.1231x; 1.1231x over previous
//
#include <hip/hip_runtime.h>
#include <math.h>

// ---------------------------------------------------------------------------
// GCN fraud-model forward:
//   out = A(relu(A(x*sig(mask) @ W1) + b1) @ (W2@Wc)) + (b2@Wc + bc)
// using linearity of aggregation A to fold W2@Wc -> [128,2].
//
// R1: CSR build (count + fill) is now XCD-range-partitioned: range =
// blockIdx.x % 8 matches the round-robin block->XCD mapping, so the
// cursor/csr slice each XCD touches (~800 KB) stays in its private L2.
// R0 profile showed fill_kernel WRITE_SIZE = 105 MB for a 6.4 MB array
// (cross-XCD line thrash); this confines scatter to L2-local lines.
// ---------------------------------------------------------------------------

constexpr int NRANGE = 8;  // = XCD count on MI355X

// ---------- tiny prep: sigmoid(mask), Wf = W2@Wc [128,2], bf = b2@Wc + bc ----
__global__ void prep_kernel(const float* __restrict__ fmask, const float* __restrict__ W2,
                            const float* __restrict__ b2, const float* __restrict__ Wc,
                            const float* __restrict__ bc, float* __restrict__ sm,
                            float* __restrict__ Wf, float* __restrict__ bf) {
  int t = threadIdx.x;
  if (t < 128) {
    sm[t] = 1.0f / (1.0f + expf(-fmask[t]));
    float w0 = 0.f, w1 = 0.f;
    for (int k = 0; k < 128; ++k) {
      float v = W2[t * 128 + k];
      w0 = fmaf(v, Wc[k * 2 + 0], w0);
      w1 = fmaf(v, Wc[k * 2 + 1], w1);
    }
    Wf[t * 2 + 0] = w0;
    Wf[t * 2 + 1] = w1;
  }
  if (t < 2) {
    float s = bc[t];
    for (int k = 0; k < 128; ++k) s = fmaf(b2[k], Wc[k * 2 + t], s);
    bf[t] = s;
  }
}

// ---------- degree count over dst, XCD-range partitioned ----------
__global__ void count_ranged_kernel(const int* __restrict__ dst, int* __restrict__ counts,
                                    int E, int rstep, int N) {
  int range = blockIdx.x & (NRANGE - 1);
  int chunk = blockIdx.x >> 3;
  int nchunks = gridDim.x >> 3;
  int per = (E + nchunks - 1) / nchunks;
  int e0 = chunk * per;
  int e1 = min(E, e0 + per);
  int lo = range * rstep;
  int hi = min(N, lo + rstep);
  for (int e = e0 + (int)threadIdx.x; e < e1; e += blockDim.x) {
    int d = dst[e];
    if (d >= lo && d < hi) atomicAdd(&counts[d], 1);
  }
}

// ---------- dinv = rsqrt(indeg + 1)  (self-loop) ----------
__global__ void dinv_kernel(const int* __restrict__ counts, float* __restrict__ dinv, int n) {
  int i = blockIdx.x * blockDim.x + threadIdx.x;
  if (i < n) dinv[i] = rsqrtf((float)(counts[i] + 1));
}

// ---------- 3-phase exclusive scan of counts (chunks of 1024) ----------
__global__ void scanA_kernel(const int* __restrict__ counts, int* __restrict__ bsum, int n) {
  __shared__ int sh[256];
  int t = threadIdx.x;
  int base = blockIdx.x * 1024 + t * 4;
  int s = 0;
#pragma unroll
  for (int j = 0; j < 4; ++j) {
    int idx = base + j;
    if (idx < n) s += counts[idx];
  }
  sh[t] = s;
  __syncthreads();
#pragma unroll
  for (int m = 128; m > 0; m >>= 1) {
    if (t < m) sh[t] += sh[t + m];
    __syncthreads();
  }
  if (t == 0) bsum[blockIdx.x] = sh[0];
}

__global__ void scanB_kernel(int* __restrict__ bsum, int nb) {
  __shared__ int sh[256];
  int t = threadIdx.x;
  int v = (t < nb) ? bsum[t] : 0;
  sh[t] = v;
  __syncthreads();
  for (int off = 1; off < 256; off <<= 1) {
    int add = (t >= off) ? sh[t - off] : 0;
    __syncthreads();
    sh[t] += add;
    __syncthreads();
  }
  if (t < nb) bsum[t] = sh[t] - v;  // exclusive
}

__global__ void scanC_kernel(const int* __restrict__ counts, const int* __restrict__ bsum,
                             int* __restrict__ offsets, int* __restrict__ cursor, int n) {
  __shared__ int sh[256];
  int t = threadIdx.x;
  int base = blockIdx.x * 1024 + t * 4;
  int c[4];
  int loc = 0;
#pragma unroll
  for (int j = 0; j < 4; ++j) {
    int idx = base + j;
    c[j] = (idx < n) ? counts[idx] : 0;
    loc += c[j];
  }
  sh[t] = loc;
  __syncthreads();
  for (int off = 1; off < 256; off <<= 1) {
    int add = (t >= off) ? sh[t - off] : 0;
    __syncthreads();
    sh[t] += add;
    __syncthreads();
  }
  int run = bsum[blockIdx.x] + sh[t] - loc;
#pragma unroll
  for (int j = 0; j < 4; ++j) {
    int idx = base + j;
    if (idx < n) {
      offsets[idx] = run;
      cursor[idx] = run;
    }
    run += c[j];
  }
}

// ---------- CSR fill (bucket edges by dst), XCD-range partitioned ----------
__global__ void fill_ranged_kernel(const int* __restrict__ src, const int* __restrict__ dst,
                                   int* __restrict__ cursor, int* __restrict__ csr,
                                   int E, int rstep, int N) {
  int range = blockIdx.x & (NRANGE - 1);
  int chunk = blockIdx.x >> 3;
  int nchunks = gridDim.x >> 3;
  int per = (E + nchunks - 1) / nchunks;
  int e0 = chunk * per;
  int e1 = min(E, e0 + per);
  int lo = range * rstep;
  int hi = min(N, lo + rstep);
  for (int e = e0 + (int)threadIdx.x; e < e1; e += blockDim.x) {
    int d = dst[e];
    if (d >= lo && d < hi) {
      int p = atomicAdd(&cursor[d], 1);
      csr[p] = src[e];
    }
  }
}

// ---------- GEMM1: H1 = (x * sm) @ W1, W1 in LDS, 32-row tiles, 4x4/thread ---
__global__ __launch_bounds__(256, 1) void gemm1_kernel(const float* __restrict__ x,
                                                       const float* __restrict__ W1,
                                                       const float* __restrict__ sm,
                                                       float* __restrict__ H1, int n) {
  __shared__ float lw[128 * 128];   // 64 KB
  __shared__ float lxt[128 * 36];   // transposed x tile, padded stride 36
  __shared__ float lsm[128];
  int t = threadIdx.x;
  if (t < 128) lsm[t] = sm[t];
  for (int i = t; i < 16384; i += 256) lw[i] = W1[i];
  __syncthreads();

  int rpb = (((n + gridDim.x - 1) / gridDim.x) + 31) & ~31;
  int r0 = blockIdx.x * rpb;
  int rend = min(n, r0 + rpb);
  int tc = t & 31, rg = t >> 5;

  for (int rb = r0; rb < rend; rb += 32) {
    __syncthreads();
    {
      int lr = t >> 3;              // 0..31 local row
      int row = rb + lr;
      int cbase = (t & 7) * 16;     // 16 consecutive features
      if (row < n) {
        const float* xp = x + (size_t)row * 128 + cbase;
#pragma unroll
        for (int j = 0; j < 4; ++j) {
          float4 v = *(const float4*)(xp + 4 * j);
          int c = cbase + 4 * j;
          lxt[(c + 0) * 36 + lr] = v.x * lsm[c + 0];
          lxt[(c + 1) * 36 + lr] = v.y * lsm[c + 1];
          lxt[(c + 2) * 36 + lr] = v.z * lsm[c + 2];
          lxt[(c + 3) * 36 + lr] = v.w * lsm[c + 3];
        }
      } else {
#pragma unroll
        for (int j = 0; j < 16; ++j) lxt[(cbase + j) * 36 + lr] = 0.f;
      }
    }
    __syncthreads();

    float4 a0 = {0, 0, 0, 0}, a1 = {0, 0, 0, 0}, a2 = {0, 0, 0, 0}, a3 = {0, 0, 0, 0};
    const float* wp = lw + tc * 4;
    const float* xp = lxt + rg * 4;
#pragma unroll 8
    for (int k = 0; k < 128; ++k) {
      float4 wv = *(const float4*)(wp + k * 128);
      float4 xv = *(const float4*)(xp + k * 36);
      a0.x = fmaf(xv.x, wv.x, a0.x); a0.y = fmaf(xv.x, wv.y, a0.y);
      a0.z = fmaf(xv.x, wv.z, a0.z); a0.w = fmaf(xv.x, wv.w, a0.w);
      a1.x = fmaf(xv.y, wv.x, a1.x); a1.y = fmaf(xv.y, wv.y, a1.y);
      a1.z = fmaf(xv.y, wv.z, a1.z); a1.w = fmaf(xv.y, wv.w, a1.w);
      a2.x = fmaf(xv.z, wv.x, a2.x); a2.y = fmaf(xv.z, wv.y, a2.y);
      a2.z = fmaf(xv.z, wv.z, a2.z); a2.w = fmaf(xv.z, wv.w, a2.w);
      a3.x = fmaf(xv.w, wv.x, a3.x); a3.y = fmaf(xv.w, wv.y, a3.y);
      a3.z = fmaf(xv.w, wv.z, a3.z); a3.w = fmaf(xv.w, wv.w, a3.w);
    }
    int colb = tc * 4;
    int rowb = rb + rg * 4;
    if (rowb + 0 < n) *(float4*)(H1 + (size_t)(rowb + 0) * 128 + colb) = a0;
    if (rowb + 1 < n) *(float4*)(H1 + (size_t)(rowb + 1) * 128 + colb) = a1;
    if (rowb + 2 < n) *(float4*)(H1 + (size_t)(rowb + 2) * 128 + colb) = a2;
    if (rowb + 3 < n) *(float4*)(H1 + (size_t)(rowb + 3) * 128 + colb) = a3;
  }
}

// ---------- agg1 (wave per node): h1 = relu(A(H1pre)+b1) in regs, Z = h1@Wf --
__global__ __launch_bounds__(256) void agg1_kernel(
    const float* __restrict__ H1, const int* __restrict__ csr,
    const int* __restrict__ offsets, const int* __restrict__ counts,
    const float* __restrict__ dinv, const float* __restrict__ b1,
    const float* __restrict__ Wf, float* __restrict__ Z, int n) {
  int lane = threadIdx.x & 63;
  int node = blockIdx.x * 4 + (threadIdx.x >> 6);
  if (node >= n) return;
  int c0 = lane * 2;

  float di = dinv[node];
  float2 acc = *(const float2*)(H1 + (size_t)node * 128 + c0);  // self-loop
  float dii = di * di;
  acc.x *= dii;
  acc.y *= dii;

  int off = offsets[node];
  int cnt = counts[node];
  int e = 0;
  for (; e + 2 <= cnt; e += 2) {
    int s0 = csr[off + e];
    int s1 = csr[off + e + 1];
    float w0 = dinv[s0] * di;
    float w1 = dinv[s1] * di;
    float2 h0 = *(const float2*)(H1 + (size_t)s0 * 128 + c0);
    float2 h1 = *(const float2*)(H1 + (size_t)s1 * 128 + c0);
    acc.x = fmaf(h0.x, w0, acc.x); acc.y = fmaf(h0.y, w0, acc.y);
    acc.x = fmaf(h1.x, w1, acc.x); acc.y = fmaf(h1.y, w1, acc.y);
  }
  if (e < cnt) {
    int s0 = csr[off + e];
    float w0 = dinv[s0] * di;
    float2 h0 = *(const float2*)(H1 + (size_t)s0 * 128 + c0);
    acc.x = fmaf(h0.x, w0, acc.x); acc.y = fmaf(h0.y, w0, acc.y);
  }

  float2 bb = *(const float2*)(b1 + c0);
  float v0 = acc.x + bb.x; v0 = v0 > 0.f ? v0 : 0.f;
  float v1 = acc.y + bb.y; v1 = v1 > 0.f ? v1 : 0.f;

  float4 wv = *(const float4*)(Wf + c0 * 2);  // {Wf[c0][0],Wf[c0][1],Wf[c0+1][0],Wf[c0+1][1]}
  float z0 = v0 * wv.x + v1 * wv.z;
  float z1 = v0 * wv.y + v1 * wv.w;
#pragma unroll
  for (int m = 32; m > 0; m >>= 1) {
    z0 += __shfl_xor(z0, m, 64);
    z1 += __shfl_xor(z1, m, 64);
  }
  if (lane == 0) {
    Z[(size_t)node * 2 + 0] = z0;
    Z[(size_t)node * 2 + 1] = z1;
  }
}

// ---------- agg2 (thread per node): out = A(Z) + bf ----------
__global__ void agg2_kernel(const float* __restrict__ Zbuf, const int* __restrict__ csr,
                            const int* __restrict__ offsets, const int* __restrict__ counts,
                            const float* __restrict__ dinv, const float* __restrict__ bf,
                            float* __restrict__ out, int n) {
  int i = blockIdx.x * blockDim.x + threadIdx.x;
  if (i >= n) return;
  float di = dinv[i];
  float2 z = *(const float2*)(Zbuf + (size_t)i * 2);
  float dii = di * di;
  float ax = z.x * dii, ay = z.y * dii;
  int off = offsets[i], cnt = counts[i];
  for (int e = 0; e < cnt; ++e) {
    int s = csr[off + e];
    float w = dinv[s] * di;
    float2 zs = *(const float2*)(Zbuf + (size_t)s * 2);
    ax = fmaf(zs.x, w, ax);
    ay = fmaf(zs.y, w, ay);
  }
  out[(size_t)i * 2 + 0] = ax + bf[0];
  out[(size_t)i * 2 + 1] = ay + bf[1];
}

extern "C" void kernel_launch(void* const* d_in, const int* in_sizes, int n_in,
                              void* d_out, int out_size, void* d_ws, size_t ws_size,
                              hipStream_t stream) {
  const float* x = (const float*)d_in[0];
  const int* ei = (const int*)d_in[1];
  const float* fmask = (const float*)d_in[2];
  const float* W1 = (const float*)d_in[3];
  const float* b1 = (const float*)d_in[4];
  const float* W2 = (const float*)d_in[5];
  const float* b2 = (const float*)d_in[6];
  const float* Wc = (const float*)d_in[7];
  const float* bc = (const float*)d_in[8];

  int N = in_sizes[0] / 128;
  int E = in_sizes[1] / 2;
  const int* src = ei;
  const int* dst = ei + E;

  char* base = (char*)d_ws;
  size_t o = 0;
  auto take = [&](size_t bytes) -> char* {
    char* p = base + o;
    o = (o + bytes + 255) & ~(size_t)255;
    return p;
  };
  int* counts = (int*)take((size_t)N * 4);
  int* offsets = (int*)take((size_t)N * 4);
  int* cursor = (int*)take((size_t)N * 4);
  int* bsum = (int*)take(256 * 4);
  float* dinv = (float*)take((size_t)N * 4);
  int* csr = (int*)take((size_t)E * 4);
  float* H1 = (float*)take((size_t)N * 128 * 4);
  float* Zb = (float*)take((size_t)N * 2 * 4);
  float* sm = (float*)take(128 * 4);
  float* Wf = (float*)take(256 * 4);
  float* bf = (float*)take(2 * 4);
  (void)ws_size;
  (void)n_in;
  (void)out_size;

  int rstep = (N + NRANGE - 1) / NRANGE;   // dst range per XCD
  int nchunks = 256;                       // edge chunks per range
  int rgrid = NRANGE * nchunks;            // range = blockIdx % 8 -> XCD id

  hipMemsetAsync(counts, 0, (size_t)N * 4, stream);
  prep_kernel<<<1, 128, 0, stream>>>(fmask, W2, b2, Wc, bc, sm, Wf, bf);
  count_ranged_kernel<<<rgrid, 256, 0, stream>>>(dst, counts, E, rstep, N);
  dinv_kernel<<<(N + 255) / 256, 256, 0, stream>>>(counts, dinv, N);
  int nb = (N + 1023) / 1024;
  scanA_kernel<<<nb, 256, 0, stream>>>(counts, bsum, N);
  scanB_kernel<<<1, 256, 0, stream>>>(bsum, nb);
  scanC_kernel<<<nb, 256, 0, stream>>>(counts, bsum, offsets, cursor, N);
  fill_ranged_kernel<<<rgrid, 256, 0, stream>>>(src, dst, cursor, csr, E, rstep, N);
  gemm1_kernel<<<256, 256, 0, stream>>>(x, W1, sm, H1, N);
  agg1_kernel<<<(N + 3) / 4, 256, 0, stream>>>(H1, csr, offsets, counts, dinv, b1, Wf, Zb, N);
  agg2_kernel<<<(N + 255) / 256, 256, 0, stream>>>(Zb, csr, offsets, counts, dinv, bf,
                                                   (float*)d_out, N);
}

// Round 3
// 343.054 us; speedup vs baseline: 1.2489x; 1.1120x over previous
//
#include <hip/hip_runtime.h>
#include <math.h>

// ---------------------------------------------------------------------------
// GCN fraud-model forward:
//   out = A(relu(A(x*sig(mask) @ W1) + b1) @ (W2@Wc)) + (b2@Wc + bc)
// A-linearity folds W2@Wc -> [128,2].
//
// R1: CSR build XCD-range-partitioned (fill WRITE_SIZE 105MB -> ~7MB).
// R3: dinv folded into stored rows (H1n = dinv[v]*H1pre[v]; Zn = dinv[v]*z[v])
//     -> no per-edge dinv gather (saves ~100MB of line traffic), and H1n is
//     stored as packed bf16 (256B/row) -> gather traffic halves again.
// ---------------------------------------------------------------------------

constexpr int NRANGE = 8;  // = XCD count on MI355X

__device__ __forceinline__ unsigned bf16rtn(float f) {
  unsigned b = __float_as_uint(f);
  b += 0x7FFFu + ((b >> 16) & 1u);   // round-to-nearest-even
  return b >> 16;
}
__device__ __forceinline__ float2 bf2unpack(unsigned u) {
  float2 r;
  r.x = __uint_as_float(u << 16);
  r.y = __uint_as_float(u & 0xFFFF0000u);
  return r;
}

// ---------- tiny prep: sigmoid(mask), Wf = W2@Wc [128,2], bf = b2@Wc + bc ----
__global__ void prep_kernel(const float* __restrict__ fmask, const float* __restrict__ W2,
                            const float* __restrict__ b2, const float* __restrict__ Wc,
                            const float* __restrict__ bc, float* __restrict__ sm,
                            float* __restrict__ Wf, float* __restrict__ bf) {
  int t = threadIdx.x;
  if (t < 128) {
    sm[t] = 1.0f / (1.0f + expf(-fmask[t]));
    float w0 = 0.f, w1 = 0.f;
    for (int k = 0; k < 128; ++k) {
      float v = W2[t * 128 + k];
      w0 = fmaf(v, Wc[k * 2 + 0], w0);
      w1 = fmaf(v, Wc[k * 2 + 1], w1);
    }
    Wf[t * 2 + 0] = w0;
    Wf[t * 2 + 1] = w1;
  }
  if (t < 2) {
    float s = bc[t];
    for (int k = 0; k < 128; ++k) s = fmaf(b2[k], Wc[k * 2 + t], s);
    bf[t] = s;
  }
}

// ---------- degree count over dst, XCD-range partitioned ----------
__global__ void count_ranged_kernel(const int* __restrict__ dst, int* __restrict__ counts,
                                    int E, int rstep, int N) {
  int range = blockIdx.x & (NRANGE - 1);
  int chunk = blockIdx.x >> 3;
  int nchunks = gridDim.x >> 3;
  int per = (E + nchunks - 1) / nchunks;
  int e0 = chunk * per;
  int e1 = min(E, e0 + per);
  int lo = range * rstep;
  int hi = min(N, lo + rstep);
  for (int e = e0 + (int)threadIdx.x; e < e1; e += blockDim.x) {
    int d = dst[e];
    if (d >= lo && d < hi) atomicAdd(&counts[d], 1);
  }
}

// ---------- dinv = rsqrt(indeg + 1)  (self-loop) ----------
__global__ void dinv_kernel(const int* __restrict__ counts, float* __restrict__ dinv, int n) {
  int i = blockIdx.x * blockDim.x + threadIdx.x;
  if (i < n) dinv[i] = rsqrtf((float)(counts[i] + 1));
}

// ---------- 3-phase exclusive scan of counts (chunks of 1024) ----------
__global__ void scanA_kernel(const int* __restrict__ counts, int* __restrict__ bsum, int n) {
  __shared__ int sh[256];
  int t = threadIdx.x;
  int base = blockIdx.x * 1024 + t * 4;
  int s = 0;
#pragma unroll
  for (int j = 0; j < 4; ++j) {
    int idx = base + j;
    if (idx < n) s += counts[idx];
  }
  sh[t] = s;
  __syncthreads();
#pragma unroll
  for (int m = 128; m > 0; m >>= 1) {
    if (t < m) sh[t] += sh[t + m];
    __syncthreads();
  }
  if (t == 0) bsum[blockIdx.x] = sh[0];
}

__global__ void scanB_kernel(int* __restrict__ bsum, int nb) {
  __shared__ int sh[256];
  int t = threadIdx.x;
  int v = (t < nb) ? bsum[t] : 0;
  sh[t] = v;
  __syncthreads();
  for (int off = 1; off < 256; off <<= 1) {
    int add = (t >= off) ? sh[t - off] : 0;
    __syncthreads();
    sh[t] += add;
    __syncthreads();
  }
  if (t < nb) bsum[t] = sh[t] - v;  // exclusive
}

__global__ void scanC_kernel(const int* __restrict__ counts, const int* __restrict__ bsum,
                             int* __restrict__ offsets, int* __restrict__ cursor, int n) {
  __shared__ int sh[256];
  int t = threadIdx.x;
  int base = blockIdx.x * 1024 + t * 4;
  int c[4];
  int loc = 0;
#pragma unroll
  for (int j = 0; j < 4; ++j) {
    int idx = base + j;
    c[j] = (idx < n) ? counts[idx] : 0;
    loc += c[j];
  }
  sh[t] = loc;
  __syncthreads();
  for (int off = 1; off < 256; off <<= 1) {
    int add = (t >= off) ? sh[t - off] : 0;
    __syncthreads();
    sh[t] += add;
    __syncthreads();
  }
  int run = bsum[blockIdx.x] + sh[t] - loc;
#pragma unroll
  for (int j = 0; j < 4; ++j) {
    int idx = base + j;
    if (idx < n) {
      offsets[idx] = run;
      cursor[idx] = run;
    }
    run += c[j];
  }
}

// ---------- CSR fill (bucket edges by dst), XCD-range partitioned ----------
__global__ void fill_ranged_kernel(const int* __restrict__ src, const int* __restrict__ dst,
                                   int* __restrict__ cursor, int* __restrict__ csr,
                                   int E, int rstep, int N) {
  int range = blockIdx.x & (NRANGE - 1);
  int chunk = blockIdx.x >> 3;
  int nchunks = gridDim.x >> 3;
  int per = (E + nchunks - 1) / nchunks;
  int e0 = chunk * per;
  int e1 = min(E, e0 + per);
  int lo = range * rstep;
  int hi = min(N, lo + rstep);
  for (int e = e0 + (int)threadIdx.x; e < e1; e += blockDim.x) {
    int d = dst[e];
    if (d >= lo && d < hi) {
      int p = atomicAdd(&cursor[d], 1);
      csr[p] = src[e];
    }
  }
}

// ---------- GEMM1: H1n = dinv[row] * ((x*sm) @ W1), packed bf16 ----------
__global__ __launch_bounds__(256, 1) void gemm1_kernel(const float* __restrict__ x,
                                                       const float* __restrict__ W1,
                                                       const float* __restrict__ sm,
                                                       const float* __restrict__ dinv,
                                                       unsigned* __restrict__ H1n, int n) {
  __shared__ float lw[128 * 128];   // 64 KB
  __shared__ float lxt[128 * 36];   // transposed x tile, padded stride 36
  __shared__ float lsm[128];
  int t = threadIdx.x;
  if (t < 128) lsm[t] = sm[t];
  for (int i = t; i < 16384; i += 256) lw[i] = W1[i];
  __syncthreads();

  int rpb = (((n + gridDim.x - 1) / gridDim.x) + 31) & ~31;
  int r0 = blockIdx.x * rpb;
  int rend = min(n, r0 + rpb);
  int tc = t & 31, rg = t >> 5;

  for (int rb = r0; rb < rend; rb += 32) {
    __syncthreads();
    {
      int lr = t >> 3;              // 0..31 local row
      int row = rb + lr;
      int cbase = (t & 7) * 16;     // 16 consecutive features
      if (row < n) {
        const float* xp = x + (size_t)row * 128 + cbase;
#pragma unroll
        for (int j = 0; j < 4; ++j) {
          float4 v = *(const float4*)(xp + 4 * j);
          int c = cbase + 4 * j;
          lxt[(c + 0) * 36 + lr] = v.x * lsm[c + 0];
          lxt[(c + 1) * 36 + lr] = v.y * lsm[c + 1];
          lxt[(c + 2) * 36 + lr] = v.z * lsm[c + 2];
          lxt[(c + 3) * 36 + lr] = v.w * lsm[c + 3];
        }
      } else {
#pragma unroll
        for (int j = 0; j < 16; ++j) lxt[(cbase + j) * 36 + lr] = 0.f;
      }
    }
    __syncthreads();

    float4 a0 = {0, 0, 0, 0}, a1 = {0, 0, 0, 0}, a2 = {0, 0, 0, 0}, a3 = {0, 0, 0, 0};
    const float* wp = lw + tc * 4;
    const float* xp = lxt + rg * 4;
#pragma unroll 8
    for (int k = 0; k < 128; ++k) {
      float4 wv = *(const float4*)(wp + k * 128);
      float4 xv = *(const float4*)(xp + k * 36);
      a0.x = fmaf(xv.x, wv.x, a0.x); a0.y = fmaf(xv.x, wv.y, a0.y);
      a0.z = fmaf(xv.x, wv.z, a0.z); a0.w = fmaf(xv.x, wv.w, a0.w);
      a1.x = fmaf(xv.y, wv.x, a1.x); a1.y = fmaf(xv.y, wv.y, a1.y);
      a1.z = fmaf(xv.y, wv.z, a1.z); a1.w = fmaf(xv.y, wv.w, a1.w);
      a2.x = fmaf(xv.z, wv.x, a2.x); a2.y = fmaf(xv.z, wv.y, a2.y);
      a2.z = fmaf(xv.z, wv.z, a2.z); a2.w = fmaf(xv.z, wv.w, a2.w);
      a3.x = fmaf(xv.w, wv.x, a3.x); a3.y = fmaf(xv.w, wv.y, a3.y);
      a3.z = fmaf(xv.w, wv.z, a3.z); a3.w = fmaf(xv.w, wv.w, a3.w);
    }
    int colb = tc * 4;          // column base (of 128)
    int rowb = rb + rg * 4;
    // pack 4 cols -> 2 uints, scale by dinv[row]
#pragma unroll
    for (int i = 0; i < 4; ++i) {
      int row = rowb + i;
      if (row < n) {
        float4 a = (i == 0) ? a0 : (i == 1) ? a1 : (i == 2) ? a2 : a3;
        float dv = dinv[row];
        uint2 p;
        p.x = bf16rtn(a.x * dv) | (bf16rtn(a.y * dv) << 16);
        p.y = bf16rtn(a.z * dv) | (bf16rtn(a.w * dv) << 16);
        *(uint2*)(H1n + (size_t)row * 64 + colb / 2) = p;
      }
    }
  }
}

// ---------- agg1 (wave per node): sum bf16 rows, h1 = relu(di*acc+b1),
//            Zn = di * (h1 @ Wf) ----------
__global__ __launch_bounds__(256) void agg1_kernel(
    const unsigned* __restrict__ H1n, const int* __restrict__ csr,
    const int* __restrict__ offsets, const int* __restrict__ counts,
    const float* __restrict__ dinv, const float* __restrict__ b1,
    const float* __restrict__ Wf, float* __restrict__ Zn, int n) {
  int lane = threadIdx.x & 63;
  int node = blockIdx.x * 4 + (threadIdx.x >> 6);
  if (node >= n) return;
  int c0 = lane * 2;

  float di = dinv[node];
  float2 acc = bf2unpack(H1n[(size_t)node * 64 + lane]);  // self-loop term

  int off = offsets[node];
  int cnt = counts[node];
  int e = 0;
  for (; e + 4 <= cnt; e += 4) {
    int s0 = csr[off + e + 0];
    int s1 = csr[off + e + 1];
    int s2 = csr[off + e + 2];
    int s3 = csr[off + e + 3];
    unsigned u0 = H1n[(size_t)s0 * 64 + lane];
    unsigned u1 = H1n[(size_t)s1 * 64 + lane];
    unsigned u2 = H1n[(size_t)s2 * 64 + lane];
    unsigned u3 = H1n[(size_t)s3 * 64 + lane];
    float2 h0 = bf2unpack(u0), h1v = bf2unpack(u1), h2 = bf2unpack(u2), h3 = bf2unpack(u3);
    acc.x += (h0.x + h1v.x) + (h2.x + h3.x);
    acc.y += (h0.y + h1v.y) + (h2.y + h3.y);
  }
  for (; e < cnt; ++e) {
    int s0 = csr[off + e];
    float2 h0 = bf2unpack(H1n[(size_t)s0 * 64 + lane]);
    acc.x += h0.x;
    acc.y += h0.y;
  }

  float2 bb = *(const float2*)(b1 + c0);
  float v0 = fmaf(acc.x, di, bb.x); v0 = v0 > 0.f ? v0 : 0.f;
  float v1 = fmaf(acc.y, di, bb.y); v1 = v1 > 0.f ? v1 : 0.f;

  float4 wv = *(const float4*)(Wf + c0 * 2);  // {Wf[c0][0],Wf[c0][1],Wf[c0+1][0],Wf[c0+1][1]}
  float z0 = v0 * wv.x + v1 * wv.z;
  float z1 = v0 * wv.y + v1 * wv.w;
#pragma unroll
  for (int m = 32; m > 0; m >>= 1) {
    z0 += __shfl_xor(z0, m, 64);
    z1 += __shfl_xor(z1, m, 64);
  }
  if (lane == 0) {
    Zn[(size_t)node * 2 + 0] = z0 * di;   // store dinv[node]*z
    Zn[(size_t)node * 2 + 1] = z1 * di;
  }
}

// ---------- agg2 (thread per node): out = di*(Zn[i] + sum Zn[s]) + bf ----------
__global__ void agg2_kernel(const float* __restrict__ Znb, const int* __restrict__ csr,
                            const int* __restrict__ offsets, const int* __restrict__ counts,
                            const float* __restrict__ dinv, const float* __restrict__ bf,
                            float* __restrict__ out, int n) {
  int i = blockIdx.x * blockDim.x + threadIdx.x;
  if (i >= n) return;
  float di = dinv[i];
  float2 z = *(const float2*)(Znb + (size_t)i * 2);
  float ax = z.x, ay = z.y;   // self-loop term
  int off = offsets[i], cnt = counts[i];
  for (int e = 0; e < cnt; ++e) {
    int s = csr[off + e];
    float2 zs = *(const float2*)(Znb + (size_t)s * 2);
    ax += zs.x;
    ay += zs.y;
  }
  out[(size_t)i * 2 + 0] = fmaf(ax, di, bf[0]);
  out[(size_t)i * 2 + 1] = fmaf(ay, di, bf[1]);
}

extern "C" void kernel_launch(void* const* d_in, const int* in_sizes, int n_in,
                              void* d_out, int out_size, void* d_ws, size_t ws_size,
                              hipStream_t stream) {
  const float* x = (const float*)d_in[0];
  const int* ei = (const int*)d_in[1];
  const float* fmask = (const float*)d_in[2];
  const float* W1 = (const float*)d_in[3];
  const float* b1 = (const float*)d_in[4];
  const float* W2 = (const float*)d_in[5];
  const float* b2 = (const float*)d_in[6];
  const float* Wc = (const float*)d_in[7];
  const float* bc = (const float*)d_in[8];

  int N = in_sizes[0] / 128;
  int E = in_sizes[1] / 2;
  const int* src = ei;
  const int* dst = ei + E;

  char* base = (char*)d_ws;
  size_t o = 0;
  auto take = [&](size_t bytes) -> char* {
    char* p = base + o;
    o = (o + bytes + 255) & ~(size_t)255;
    return p;
  };
  int* counts = (int*)take((size_t)N * 4);
  int* offsets = (int*)take((size_t)N * 4);
  int* cursor = (int*)take((size_t)N * 4);
  int* bsum = (int*)take(256 * 4);
  float* dinv = (float*)take((size_t)N * 4);
  int* csr = (int*)take((size_t)E * 4);
  unsigned* H1n = (unsigned*)take((size_t)N * 64 * 4);  // packed bf16 rows
  float* Zn = (float*)take((size_t)N * 2 * 4);
  float* sm = (float*)take(128 * 4);
  float* Wf = (float*)take(256 * 4);
  float* bf = (float*)take(2 * 4);
  (void)ws_size;
  (void)n_in;
  (void)out_size;

  int rstep = (N + NRANGE - 1) / NRANGE;   // dst range per XCD
  int nchunks = 256;                       // edge chunks per range
  int rgrid = NRANGE * nchunks;            // range = blockIdx % 8 -> XCD id

  hipMemsetAsync(counts, 0, (size_t)N * 4, stream);
  prep_kernel<<<1, 128, 0, stream>>>(fmask, W2, b2, Wc, bc, sm, Wf, bf);
  count_ranged_kernel<<<rgrid, 256, 0, stream>>>(dst, counts, E, rstep, N);
  dinv_kernel<<<(N + 255) / 256, 256, 0, stream>>>(counts, dinv, N);
  int nb = (N + 1023) / 1024;
  scanA_kernel<<<nb, 256, 0, stream>>>(counts, bsum, N);
  scanB_kernel<<<1, 256, 0, stream>>>(bsum, nb);
  scanC_kernel<<<nb, 256, 0, stream>>>(counts, bsum, offsets, cursor, N);
  fill_ranged_kernel<<<rgrid, 256, 0, stream>>>(src, dst, cursor, csr, E, rstep, N);
  gemm1_kernel<<<256, 256, 0, stream>>>(x, W1, sm, dinv, H1n, N);
  agg1_kernel<<<(N + 3) / 4, 256, 0, stream>>>(H1n, csr, offsets, counts, dinv, b1, Wf, Zn, N);
  agg2_kernel<<<(N + 255) / 256, 256, 0, stream>>>(Zn, csr, offsets, counts, dinv, bf,
                                                   (float*)d_out, N);
}

// Round 4
// 278.701 us; speedup vs baseline: 1.5372x; 1.2309x over previous
//
#include <hip/hip_runtime.h>
#include <math.h>

// ---------------------------------------------------------------------------
// GCN fraud-model forward:
//   out = A(relu(A(x*sig(mask) @ W1) + b1) @ (W2@Wc)) + (b2@Wc + bc)
// A-linearity folds W2@Wc -> [128,2].
//
// R1: CSR build XCD-range-partitioned (fill WRITE_SIZE 105MB -> ~7MB).
// R3: dinv folded into stored rows; H1n stored packed bf16 (256B/row).
// R4: gemm1 -> MFMA bf16 (v_mfma_f32_32x32x16_bf16). R3 profile: fp32 gemm1
//     was 101us @ 10% occupancy (84KB LDS -> 1 blk/CU) + 3M bank conflicts.
//     Now: W1 pre-transposed to bf16, staged in XOR-swizzled LDS (G4 fix),
//     x*sm -> bf16 swizzled LDS, 32 MFMA per wave, 66KB LDS -> 2 blk/CU.
// ---------------------------------------------------------------------------

constexpr int NRANGE = 8;  // = XCD count on MI355X

typedef __attribute__((ext_vector_type(8))) short bf16x8;
typedef __attribute__((ext_vector_type(16))) float f32x16;

__device__ __forceinline__ unsigned bf16rtn(float f) {
  unsigned b = __float_as_uint(f);
  b += 0x7FFFu + ((b >> 16) & 1u);   // round-to-nearest-even
  return b >> 16;
}
__device__ __forceinline__ float2 bf2unpack(unsigned u) {
  float2 r;
  r.x = __uint_as_float(u << 16);
  r.y = __uint_as_float(u & 0xFFFF0000u);
  return r;
}

// ---------- tiny prep: sigmoid(mask), Wf = W2@Wc [128,2], bf = b2@Wc + bc ----
__global__ void prep_kernel(const float* __restrict__ fmask, const float* __restrict__ W2,
                            const float* __restrict__ b2, const float* __restrict__ Wc,
                            const float* __restrict__ bc, float* __restrict__ sm,
                            float* __restrict__ Wf, float* __restrict__ bf) {
  int t = threadIdx.x;
  if (t < 128) {
    sm[t] = 1.0f / (1.0f + expf(-fmask[t]));
    float w0 = 0.f, w1 = 0.f;
    for (int k = 0; k < 128; ++k) {
      float v = W2[t * 128 + k];
      w0 = fmaf(v, Wc[k * 2 + 0], w0);
      w1 = fmaf(v, Wc[k * 2 + 1], w1);
    }
    Wf[t * 2 + 0] = w0;
    Wf[t * 2 + 1] = w1;
  }
  if (t < 2) {
    float s = bc[t];
    for (int k = 0; k < 128; ++k) s = fmaf(b2[k], Wc[k * 2 + t], s);
    bf[t] = s;
  }
}

// ---------- W1 -> bf16 transposed: W1Tg u32[j*64 + k/2] = {W1[k][j],W1[k+1][j]} ----
__global__ void w1t_kernel(const float* __restrict__ W1, unsigned* __restrict__ W1Tg) {
  int p = blockIdx.x * blockDim.x + threadIdx.x;  // 0..8191
  if (p >= 8192) return;
  int j = p >> 6;
  int kp = (p & 63) * 2;
  float a = W1[(size_t)kp * 128 + j];
  float b = W1[(size_t)(kp + 1) * 128 + j];
  W1Tg[p] = bf16rtn(a) | (bf16rtn(b) << 16);
}

// ---------- degree count over dst, XCD-range partitioned ----------
__global__ void count_ranged_kernel(const int* __restrict__ dst, int* __restrict__ counts,
                                    int E, int rstep, int N) {
  int range = blockIdx.x & (NRANGE - 1);
  int chunk = blockIdx.x >> 3;
  int nchunks = gridDim.x >> 3;
  int per = (E + nchunks - 1) / nchunks;
  int e0 = chunk * per;
  int e1 = min(E, e0 + per);
  int lo = range * rstep;
  int hi = min(N, lo + rstep);
  for (int e = e0 + (int)threadIdx.x; e < e1; e += blockDim.x) {
    int d = dst[e];
    if (d >= lo && d < hi) atomicAdd(&counts[d], 1);
  }
}

// ---------- dinv = rsqrt(indeg + 1)  (self-loop) ----------
__global__ void dinv_kernel(const int* __restrict__ counts, float* __restrict__ dinv, int n) {
  int i = blockIdx.x * blockDim.x + threadIdx.x;
  if (i < n) dinv[i] = rsqrtf((float)(counts[i] + 1));
}

// ---------- 3-phase exclusive scan of counts (chunks of 1024) ----------
__global__ void scanA_kernel(const int* __restrict__ counts, int* __restrict__ bsum, int n) {
  __shared__ int sh[256];
  int t = threadIdx.x;
  int base = blockIdx.x * 1024 + t * 4;
  int s = 0;
#pragma unroll
  for (int j = 0; j < 4; ++j) {
    int idx = base + j;
    if (idx < n) s += counts[idx];
  }
  sh[t] = s;
  __syncthreads();
#pragma unroll
  for (int m = 128; m > 0; m >>= 1) {
    if (t < m) sh[t] += sh[t + m];
    __syncthreads();
  }
  if (t == 0) bsum[blockIdx.x] = sh[0];
}

__global__ void scanB_kernel(int* __restrict__ bsum, int nb) {
  __shared__ int sh[256];
  int t = threadIdx.x;
  int v = (t < nb) ? bsum[t] : 0;
  sh[t] = v;
  __syncthreads();
  for (int off = 1; off < 256; off <<= 1) {
    int add = (t >= off) ? sh[t - off] : 0;
    __syncthreads();
    sh[t] += add;
    __syncthreads();
  }
  if (t < nb) bsum[t] = sh[t] - v;  // exclusive
}

__global__ void scanC_kernel(const int* __restrict__ counts, const int* __restrict__ bsum,
                             int* __restrict__ offsets, int* __restrict__ cursor, int n) {
  __shared__ int sh[256];
  int t = threadIdx.x;
  int base = blockIdx.x * 1024 + t * 4;
  int c[4];
  int loc = 0;
#pragma unroll
  for (int j = 0; j < 4; ++j) {
    int idx = base + j;
    c[j] = (idx < n) ? counts[idx] : 0;
    loc += c[j];
  }
  sh[t] = loc;
  __syncthreads();
  for (int off = 1; off < 256; off <<= 1) {
    int add = (t >= off) ? sh[t - off] : 0;
    __syncthreads();
    sh[t] += add;
    __syncthreads();
  }
  int run = bsum[blockIdx.x] + sh[t] - loc;
#pragma unroll
  for (int j = 0; j < 4; ++j) {
    int idx = base + j;
    if (idx < n) {
      offsets[idx] = run;
      cursor[idx] = run;
    }
    run += c[j];
  }
}

// ---------- CSR fill (bucket edges by dst), XCD-range partitioned ----------
__global__ void fill_ranged_kernel(const int* __restrict__ src, const int* __restrict__ dst,
                                   int* __restrict__ cursor, int* __restrict__ csr,
                                   int E, int rstep, int N) {
  int range = blockIdx.x & (NRANGE - 1);
  int chunk = blockIdx.x >> 3;
  int nchunks = gridDim.x >> 3;
  int per = (E + nchunks - 1) / nchunks;
  int e0 = chunk * per;
  int e1 = min(E, e0 + per);
  int lo = range * rstep;
  int hi = min(N, lo + rstep);
  for (int e = e0 + (int)threadIdx.x; e < e1; e += blockDim.x) {
    int d = dst[e];
    if (d >= lo && d < hi) {
      int p = atomicAdd(&cursor[d], 1);
      csr[p] = src[e];
    }
  }
}

// ---------- GEMM1 (MFMA): H1n = dinv[row] * ((x*sm) @ W1) in packed bf16 ----
// Block: 256 thr = 4 waves, 128 rows. LDS: W1T 32KB + A 32KB + dinv 512B.
// XOR swizzle ((row&7)<<3 in shorts) keeps ds_read_b128 at the 4-bank floor.
__global__ __launch_bounds__(256) void gemm1_mfma_kernel(
    const float* __restrict__ x, const unsigned* __restrict__ W1Tg,
    const float* __restrict__ sm, const float* __restrict__ dinv,
    unsigned* __restrict__ H1n, int n) {
  __shared__ short lw1t[16384];  // 32 KB, W1T[j][k] bf16, swizzled
  __shared__ short lA[16384];    // 32 KB, A[r][k] bf16, swizzled
  __shared__ float ldv[128];
  int t = threadIdx.x;
  int rowbase = blockIdx.x * 128;

  if (t < 128) {
    int rg = rowbase + t;
    ldv[t] = (rg < n) ? dinv[rg] : 0.f;
  }
  // stage W1T: 2048 16B granules
#pragma unroll
  for (int i = 0; i < 8; ++i) {
    int g = t + i * 256;
    int j = g >> 4;
    int c8 = (g & 15) * 8;
    uint4 v = *(const uint4*)(W1Tg + j * 64 + (c8 >> 1));
    int so = (j * 128 + c8) ^ ((j & 7) << 3);
    *(uint4*)(&lw1t[so]) = v;
  }
  // stage A = bf16(x*sm): 2048 granules
#pragma unroll
  for (int i = 0; i < 8; ++i) {
    int g = t + i * 256;
    int r = g >> 4;
    int c8 = (g & 15) * 8;
    int rowg = rowbase + r;
    uint4 p = {0, 0, 0, 0};
    if (rowg < n) {
      const float* xp = x + (size_t)rowg * 128 + c8;
      float4 xa = *(const float4*)(xp);
      float4 xb = *(const float4*)(xp + 4);
      float4 sa = *(const float4*)(sm + c8);
      float4 sb = *(const float4*)(sm + c8 + 4);
      p.x = bf16rtn(xa.x * sa.x) | (bf16rtn(xa.y * sa.y) << 16);
      p.y = bf16rtn(xa.z * sa.z) | (bf16rtn(xa.w * sa.w) << 16);
      p.z = bf16rtn(xb.x * sb.x) | (bf16rtn(xb.y * sb.y) << 16);
      p.w = bf16rtn(xb.z * sb.z) | (bf16rtn(xb.w * sb.w) << 16);
    }
    int so = (r * 128 + c8) ^ ((r & 7) << 3);
    *(uint4*)(&lA[so]) = p;
  }
  __syncthreads();

  int l = t & 63;
  int w = t >> 6;      // wave id: rows [w*32, w*32+32)
  int wbase = w * 32;
  int lp = l & 31;
  int lhi = l >> 5;

  bf16x8 af[8];
#pragma unroll
  for (int kb = 0; kb < 8; ++kb) {
    int row = wbase + lp;
    int so = (row * 128 + kb * 16 + lhi * 8) ^ ((row & 7) << 3);
    af[kb] = *(const bf16x8*)(&lA[so]);
  }
  f32x16 acc0 = {}, acc1 = {}, acc2 = {}, acc3 = {};
#pragma unroll
  for (int kb = 0; kb < 8; ++kb) {
    int ko = kb * 16 + lhi * 8;
    int sw = (lp & 7) << 3;
    bf16x8 b0 = *(const bf16x8*)(&lw1t[((lp + 0) * 128 + ko) ^ sw]);
    bf16x8 b1 = *(const bf16x8*)(&lw1t[((lp + 32) * 128 + ko) ^ sw]);
    bf16x8 b2 = *(const bf16x8*)(&lw1t[((lp + 64) * 128 + ko) ^ sw]);
    bf16x8 b3 = *(const bf16x8*)(&lw1t[((lp + 96) * 128 + ko) ^ sw]);
    acc0 = __builtin_amdgcn_mfma_f32_32x32x16_bf16(af[kb], b0, acc0, 0, 0, 0);
    acc1 = __builtin_amdgcn_mfma_f32_32x32x16_bf16(af[kb], b1, acc1, 0, 0, 0);
    acc2 = __builtin_amdgcn_mfma_f32_32x32x16_bf16(af[kb], b2, acc2, 0, 0, 0);
    acc3 = __builtin_amdgcn_mfma_f32_32x32x16_bf16(af[kb], b3, acc3, 0, 0, 0);
  }

  // epilogue: D row = (r&3)+8*(r>>2)+4*lhi, col = t32*32+lp. Pack col pairs
  // via shfl_xor(1); even lanes store u32 col-pair -> H1n[row][t32*16+lp/2].
#pragma unroll
  for (int r = 0; r < 16; ++r) {
    int row_local = wbase + (r & 3) + 8 * (r >> 2) + 4 * lhi;
    float dv = ldv[row_local];
    int rowg = rowbase + row_local;
    bool ok = (rowg < n) && !(l & 1);
    size_t base = (size_t)rowg * 64 + (lp >> 1);
    {
      float v = acc0[r] * dv; float o = __shfl_xor(v, 1, 64);
      if (ok) H1n[base + 0] = bf16rtn(v) | (bf16rtn(o) << 16);
    }
    {
      float v = acc1[r] * dv; float o = __shfl_xor(v, 1, 64);
      if (ok) H1n[base + 16] = bf16rtn(v) | (bf16rtn(o) << 16);
    }
    {
      float v = acc2[r] * dv; float o = __shfl_xor(v, 1, 64);
      if (ok) H1n[base + 32] = bf16rtn(v) | (bf16rtn(o) << 16);
    }
    {
      float v = acc3[r] * dv; float o = __shfl_xor(v, 1, 64);
      if (ok) H1n[base + 48] = bf16rtn(v) | (bf16rtn(o) << 16);
    }
  }
}

// ---------- agg1 (wave per node): sum bf16 rows, h1 = relu(di*acc+b1),
//            Zn = di * (h1 @ Wf) ----------
__global__ __launch_bounds__(256) void agg1_kernel(
    const unsigned* __restrict__ H1n, const int* __restrict__ csr,
    const int* __restrict__ offsets, const int* __restrict__ counts,
    const float* __restrict__ dinv, const float* __restrict__ b1,
    const float* __restrict__ Wf, float* __restrict__ Zn, int n) {
  int lane = threadIdx.x & 63;
  int node = blockIdx.x * 4 + (threadIdx.x >> 6);
  if (node >= n) return;
  int c0 = lane * 2;

  float di = dinv[node];
  float2 acc = bf2unpack(H1n[(size_t)node * 64 + lane]);  // self-loop term

  int off = offsets[node];
  int cnt = counts[node];
  int e = 0;
  for (; e + 4 <= cnt; e += 4) {
    int s0 = csr[off + e + 0];
    int s1 = csr[off + e + 1];
    int s2 = csr[off + e + 2];
    int s3 = csr[off + e + 3];
    unsigned u0 = H1n[(size_t)s0 * 64 + lane];
    unsigned u1 = H1n[(size_t)s1 * 64 + lane];
    unsigned u2 = H1n[(size_t)s2 * 64 + lane];
    unsigned u3 = H1n[(size_t)s3 * 64 + lane];
    float2 h0 = bf2unpack(u0), h1v = bf2unpack(u1), h2 = bf2unpack(u2), h3 = bf2unpack(u3);
    acc.x += (h0.x + h1v.x) + (h2.x + h3.x);
    acc.y += (h0.y + h1v.y) + (h2.y + h3.y);
  }
  for (; e < cnt; ++e) {
    int s0 = csr[off + e];
    float2 h0 = bf2unpack(H1n[(size_t)s0 * 64 + lane]);
    acc.x += h0.x;
    acc.y += h0.y;
  }

  float2 bb = *(const float2*)(b1 + c0);
  float v0 = fmaf(acc.x, di, bb.x); v0 = v0 > 0.f ? v0 : 0.f;
  float v1 = fmaf(acc.y, di, bb.y); v1 = v1 > 0.f ? v1 : 0.f;

  float4 wv = *(const float4*)(Wf + c0 * 2);
  float z0 = v0 * wv.x + v1 * wv.z;
  float z1 = v0 * wv.y + v1 * wv.w;
#pragma unroll
  for (int m = 32; m > 0; m >>= 1) {
    z0 += __shfl_xor(z0, m, 64);
    z1 += __shfl_xor(z1, m, 64);
  }
  if (lane == 0) {
    Zn[(size_t)node * 2 + 0] = z0 * di;
    Zn[(size_t)node * 2 + 1] = z1 * di;
  }
}

// ---------- agg2 (thread per node): out = di*(Zn[i] + sum Zn[s]) + bf ----------
__global__ void agg2_kernel(const float* __restrict__ Znb, const int* __restrict__ csr,
                            const int* __restrict__ offsets, const int* __restrict__ counts,
                            const float* __restrict__ dinv, const float* __restrict__ bf,
                            float* __restrict__ out, int n) {
  int i = blockIdx.x * blockDim.x + threadIdx.x;
  if (i >= n) return;
  float di = dinv[i];
  float2 z = *(const float2*)(Znb + (size_t)i * 2);
  float ax = z.x, ay = z.y;   // self-loop term
  int off = offsets[i], cnt = counts[i];
  for (int e = 0; e < cnt; ++e) {
    int s = csr[off + e];
    float2 zs = *(const float2*)(Znb + (size_t)s * 2);
    ax += zs.x;
    ay += zs.y;
  }
  out[(size_t)i * 2 + 0] = fmaf(ax, di, bf[0]);
  out[(size_t)i * 2 + 1] = fmaf(ay, di, bf[1]);
}

extern "C" void kernel_launch(void* const* d_in, const int* in_sizes, int n_in,
                              void* d_out, int out_size, void* d_ws, size_t ws_size,
                              hipStream_t stream) {
  const float* x = (const float*)d_in[0];
  const int* ei = (const int*)d_in[1];
  const float* fmask = (const float*)d_in[2];
  const float* W1 = (const float*)d_in[3];
  const float* b1 = (const float*)d_in[4];
  const float* W2 = (const float*)d_in[5];
  const float* b2 = (const float*)d_in[6];
  const float* Wc = (const float*)d_in[7];
  const float* bc = (const float*)d_in[8];

  int N = in_sizes[0] / 128;
  int E = in_sizes[1] / 2;
  const int* src = ei;
  const int* dst = ei + E;

  char* base = (char*)d_ws;
  size_t o = 0;
  auto take = [&](size_t bytes) -> char* {
    char* p = base + o;
    o = (o + bytes + 255) & ~(size_t)255;
    return p;
  };
  int* counts = (int*)take((size_t)N * 4);
  int* offsets = (int*)take((size_t)N * 4);
  int* cursor = (int*)take((size_t)N * 4);
  int* bsum = (int*)take(256 * 4);
  float* dinv = (float*)take((size_t)N * 4);
  int* csr = (int*)take((size_t)E * 4);
  unsigned* H1n = (unsigned*)take((size_t)N * 64 * 4);  // packed bf16 rows
  float* Zn = (float*)take((size_t)N * 2 * 4);
  float* sm = (float*)take(128 * 4);
  float* Wf = (float*)take(256 * 4);
  float* bf = (float*)take(2 * 4);
  unsigned* W1Tg = (unsigned*)take(8192 * 4);           // W1^T bf16 packed
  (void)ws_size;
  (void)n_in;
  (void)out_size;

  int rstep = (N + NRANGE - 1) / NRANGE;   // dst range per XCD
  int nchunks = 256;                       // edge chunks per range
  int rgrid = NRANGE * nchunks;            // range = blockIdx % 8 -> XCD id

  hipMemsetAsync(counts, 0, (size_t)N * 4, stream);
  prep_kernel<<<1, 128, 0, stream>>>(fmask, W2, b2, Wc, bc, sm, Wf, bf);
  w1t_kernel<<<32, 256, 0, stream>>>(W1, W1Tg);
  count_ranged_kernel<<<rgrid, 256, 0, stream>>>(dst, counts, E, rstep, N);
  dinv_kernel<<<(N + 255) / 256, 256, 0, stream>>>(counts, dinv, N);
  int nb = (N + 1023) / 1024;
  scanA_kernel<<<nb, 256, 0, stream>>>(counts, bsum, N);
  scanB_kernel<<<1, 256, 0, stream>>>(bsum, nb);
  scanC_kernel<<<nb, 256, 0, stream>>>(counts, bsum, offsets, cursor, N);
  fill_ranged_kernel<<<rgrid, 256, 0, stream>>>(src, dst, cursor, csr, E, rstep, N);
  gemm1_mfma_kernel<<<(N + 127) / 128, 256, 0, stream>>>(x, W1Tg, sm, dinv, H1n, N);
  agg1_kernel<<<(N + 3) / 4, 256, 0, stream>>>(H1n, csr, offsets, counts, dinv, b1, Wf, Zn, N);
  agg2_kernel<<<(N + 255) / 256, 256, 0, stream>>>(Zn, csr, offsets, counts, dinv, bf,
                                                   (float*)d_out, N);
}